// Round 12
// baseline (157.817 us; speedup 1.0000x reference)
//
#include <hip/hip_runtime.h>
#include <hip/hip_fp16.h>
#include <math.h>

#define N_NODES   50000
#define N_EDGES   800000
#define N_FEAT    128
#define HIDDEN    64
#define EMBED     300
#define N_CLASSES 10
#define N_GRAPHS  500
#define LEAKY     0.01f
#define SCAN_BLOCKS 196
#define NB_FILL   3125
#define NB_G2Q    3125

typedef __attribute__((ext_vector_type(4))) _Float16 half4f;
typedef __attribute__((ext_vector_type(8))) _Float16 half8;
typedef __attribute__((ext_vector_type(4))) float f32x4;

__device__ __forceinline__ float pk_w(unsigned p) {
    return __half2float(__ushort_as_half((unsigned short)(p >> 16)));
}

// ---------------- kA: zero(deg,gs,ge,aggs) + W1T + W2T ----------------
__global__ void kA(int* deg, int* gs, int* ge, unsigned long long* aggs,
                   const float* __restrict__ W1, __half* __restrict__ W1T,
                   const float* __restrict__ W2, __half* __restrict__ W2T) {
    int bid = blockIdx.x, tid = threadIdx.x;
    if (bid < 196) {
        int i = bid * 256 + tid;
        if (i < N_NODES) deg[i] = 0;
        if (i < N_GRAPHS) { gs[i] = 0; ge[i] = 0; }
        if (bid == 0 && tid < SCAN_BLOCKS) aggs[tid] = 0ULL;
    } else if (bid < 228) {
        int idx = (bid - 196) * 256 + tid;
        int n = idx >> 7, k = idx & 127;
        W1T[idx] = __float2half(W1[k * HIDDEN + n]);
    } else {
        int idx = (bid - 228) * 256 + tid;
        int n = idx >> 6, k = idx & 63;
        W2T[idx] = __float2half(W2[k * HIDDEN + n]);
    }
}

// ---------------- degree count + per-edge rank ----------------
__global__ void k_deg_rank(const int* __restrict__ dst, int* deg, int* rank) {
    int e = blockIdx.x * 256 + threadIdx.x;
    if (e < N_EDGES) rank[e] = atomicAdd(&deg[dst[e]], 1);
}

// ---------------- single-pass scan (decoupled lookback), + dis ----------------
__global__ __launch_bounds__(256) void k_scan(const int* __restrict__ deg,
                                              int* __restrict__ row_start,
                                              unsigned long long* __restrict__ aggs,
                                              float* __restrict__ dis) {
    __shared__ int wsum[4];
    int bid = blockIdx.x, tid = threadIdx.x;
    int i = bid * 256 + tid;
    int v = (i < N_NODES) ? deg[i] : 0;
    int lane = tid & 63, wid = tid >> 6;
    int s = v;
    #pragma unroll
    for (int off = 1; off < 64; off <<= 1) {
        int t = __shfl_up(s, off, 64);
        if (lane >= off) s += t;
    }
    if (lane == 63) wsum[wid] = s;
    __syncthreads();
    int woff = 0;
    for (int w = 0; w < wid; ++w) woff += wsum[w];
    int total = wsum[0] + wsum[1] + wsum[2] + wsum[3];

    if (tid == 0)
        atomicExch(&aggs[bid], (1ULL << 32) | (unsigned long long)(unsigned)total);

    int pv = 0;
    if (tid < bid) {
        unsigned long long g;
        do { g = atomicAdd(&aggs[tid], 0ULL); } while (!(g >> 32));
        pv = (int)(unsigned)(g & 0xFFFFFFFFULL);
    }
    #pragma unroll
    for (int off = 32; off > 0; off >>= 1) pv += __shfl_xor(pv, off, 64);
    __syncthreads();
    if (lane == 0) wsum[wid] = pv;
    __syncthreads();
    int prefix = wsum[0] + wsum[1] + wsum[2] + wsum[3];

    if (i < N_NODES) {
        row_start[i] = woff + s - v + prefix;
        dis[i] = rsqrtf((float)(deg[i] + 1));
    }
    if (i == 0) row_start[N_NODES] = N_EDGES;
}

// ---------------- kB: CSR fill (0..3124) || MFMA gemm1 (3125..3906) ----------------
__global__ __launch_bounds__(256) void kB(const int* __restrict__ src, const int* __restrict__ dst,
                                          const int* __restrict__ rank, const int* __restrict__ row_start,
                                          const float* __restrict__ dis, unsigned* __restrict__ pk,
                                          const float* __restrict__ x, const __half* __restrict__ W1T,
                                          __half* __restrict__ h1) {
    if (blockIdx.x < NB_FILL) {
        int e = blockIdx.x * 256 + threadIdx.x;
        if (e < N_EDGES) {
            int s = src[e], d = dst[e];
            float w = dis[s] * dis[d];
            unsigned short wh = __half_as_ushort(__float2half(w));
            pk[row_start[d] + rank[e]] = (unsigned)s | ((unsigned)wh << 16);
        }
        return;
    }
    int tid = threadIdx.x, wid = tid >> 6, lane = tid & 63;
    int r16 = lane & 15, kg = lane >> 4;
    int rowbase = (blockIdx.x - NB_FILL) * 64 + wid * 16;
    int arow = rowbase + r16;
    bool avalid = arow < N_NODES;
    const float* xr = x + (size_t)arow * N_FEAT;

    half8 a[4];
    #pragma unroll
    for (int kt = 0; kt < 4; ++kt) {
        int k0 = kt * 32 + kg * 8;
        float4 u = avalid ? *(const float4*)(xr + k0)     : make_float4(0.f, 0.f, 0.f, 0.f);
        float4 v = avalid ? *(const float4*)(xr + k0 + 4) : make_float4(0.f, 0.f, 0.f, 0.f);
        a[kt][0] = (_Float16)u.x; a[kt][1] = (_Float16)u.y;
        a[kt][2] = (_Float16)u.z; a[kt][3] = (_Float16)u.w;
        a[kt][4] = (_Float16)v.x; a[kt][5] = (_Float16)v.y;
        a[kt][6] = (_Float16)v.z; a[kt][7] = (_Float16)v.w;
    }
    #pragma unroll
    for (int nt = 0; nt < 4; ++nt) {
        f32x4 acc = {0.f, 0.f, 0.f, 0.f};
        const _Float16* wp = (const _Float16*)W1T + (size_t)(nt * 16 + r16) * N_FEAT + kg * 8;
        #pragma unroll
        for (int kt = 0; kt < 4; ++kt) {
            half8 b = *(const half8*)(wp + kt * 32);
            acc = __builtin_amdgcn_mfma_f32_16x16x32_f16(a[kt], b, acc, 0, 0, 0);
        }
        int col = nt * 16 + r16;
        #pragma unroll
        for (int r = 0; r < 4; ++r) {
            int row = rowbase + kg * 4 + r;
            if (row < N_NODES) h1[(size_t)row * HIDDEN + col] = __float2half(acc[r]);
        }
    }
}

// ---------------- gather cores ----------------
__device__ __forceinline__ void gacc(const __half* __restrict__ h, unsigned p, int q, float4& a) {
    float w = pk_w(p);
    half4f hv = *(const half4f*)(h + ((size_t)(p & 0xFFFFu)) * HIDDEN + (q << 2));
    a.x = fmaf(w, (float)hv.x, a.x);
    a.y = fmaf(w, (float)hv.y, a.y);
    a.z = fmaf(w, (float)hv.z, a.z);
    a.w = fmaf(w, (float)hv.w, a.w);
}

__device__ __forceinline__ void gather4pk(const __half* __restrict__ h,
                                          const unsigned* __restrict__ pk,
                                          int s, int e, int lane, int g4, int q,
                                          float4& acc) {
    for (int cs = s; cs < e; cs += 64) {
        unsigned pkv = (cs + lane < e) ? pk[cs + lane] : 0u;
        int avail = e - cs; if (avail > 64) avail = 64;
        int iters = (avail + 3) >> 2;
        #pragma unroll 2
        for (int t = 0; t < iters; ++t)
            gacc(h, __shfl(pkv, t * 4 + g4, 64), q, acc);
    }
}

// quad gather: 4 nodes' first-chunk pk loads issued together, 4 interleaved streams
__device__ __forceinline__ void gather4x(const __half* __restrict__ h,
                                         const unsigned* __restrict__ pk,
                                         const int rs[5], int lane, int g4, int q,
                                         float4 a[4]) {
    unsigned pv0 = (rs[0] + lane < rs[1]) ? pk[rs[0] + lane] : 0u;
    unsigned pv1 = (rs[1] + lane < rs[2]) ? pk[rs[1] + lane] : 0u;
    unsigned pv2 = (rs[2] + lane < rs[3]) ? pk[rs[2] + lane] : 0u;
    unsigned pv3 = (rs[3] + lane < rs[4]) ? pk[rs[3] + lane] : 0u;
    int n0 = rs[1] - rs[0]; if (n0 > 64) n0 = 64;
    int n1 = rs[2] - rs[1]; if (n1 > 64) n1 = 64;
    int n2 = rs[3] - rs[2]; if (n2 > 64) n2 = 64;
    int n3 = rs[4] - rs[3]; if (n3 > 64) n3 = 64;
    int it0 = (n0 + 3) >> 2, it1 = (n1 + 3) >> 2;
    int it2 = (n2 + 3) >> 2, it3 = (n3 + 3) >> 2;
    int m01 = it0 > it1 ? it0 : it1;
    int m23 = it2 > it3 ? it2 : it3;
    int itm = m01 > m23 ? m01 : m23;
    for (int t = 0; t < itm; ++t) {
        int sl = t * 4 + g4;
        if (t < it0) gacc(h, __shfl(pv0, sl, 64), q, a[0]);
        if (t < it1) gacc(h, __shfl(pv1, sl, 64), q, a[1]);
        if (t < it2) gacc(h, __shfl(pv2, sl, 64), q, a[2]);
        if (t < it3) gacc(h, __shfl(pv3, sl, 64), q, a[3]);
    }
    if (rs[1] - rs[0] > 64) gather4pk(h, pk, rs[0] + 64, rs[1], lane, g4, q, a[0]);
    if (rs[2] - rs[1] > 64) gather4pk(h, pk, rs[1] + 64, rs[2], lane, g4, q, a[1]);
    if (rs[3] - rs[2] > 64) gather4pk(h, pk, rs[2] + 64, rs[3], lane, g4, q, a[2]);
    if (rs[4] - rs[3] > 64) gather4pk(h, pk, rs[3] + 64, rs[4], lane, g4, q, a[3]);
}

__device__ __forceinline__ void xreduce(float4& a) {
    a.x += __shfl_xor(a.x, 16, 64); a.y += __shfl_xor(a.y, 16, 64);
    a.z += __shfl_xor(a.z, 16, 64); a.w += __shfl_xor(a.w, 16, 64);
    a.x += __shfl_xor(a.x, 32, 64); a.y += __shfl_xor(a.y, 32, 64);
    a.z += __shfl_xor(a.z, 32, 64); a.w += __shfl_xor(a.w, 32, 64);
}

// ---------------- k_gg: quad-gather + MFMA gemm2, 16 nodes/block ----------------
__global__ __launch_bounds__(256) void k_gg(const __half* __restrict__ h1,
                                            const unsigned* __restrict__ pk,
                                            const int* __restrict__ row_start,
                                            const float* __restrict__ dis,
                                            const float* __restrict__ b1,
                                            const __half* __restrict__ W2T,
                                            __half* __restrict__ h2) {
    __shared__ __align__(16) __half sa[16 * 72];
    int tid = threadIdx.x, wid = tid >> 6, lane = tid & 63;
    int g4 = lane >> 4, q = lane & 15;
    int base = blockIdx.x * 16 + wid * 4;   // 50000 = 3125*16
    int rs[5];
    #pragma unroll
    for (int i = 0; i < 5; ++i) rs[i] = row_start[base + i];

    float4 a[4];
    #pragma unroll
    for (int i = 0; i < 4; ++i) a[i] = make_float4(0.f, 0.f, 0.f, 0.f);
    gather4x(h1, pk, rs, lane, g4, q, a);
    #pragma unroll
    for (int i = 0; i < 4; ++i) xreduce(a[i]);

    float4 bv = *(const float4*)(b1 + (q << 2));
    if (g4 == 0) {
        #pragma unroll
        for (int i = 0; i < 4; ++i) {
            int node = base + i;
            float dd = dis[node]; dd *= dd;
            half4f sv = *(const half4f*)(h1 + (size_t)node * HIDDEN + (q << 2));
            half4f r;
            r.x = (_Float16)fmaxf(fmaf((float)sv.x, dd, bv.x) + a[i].x, 0.f);
            r.y = (_Float16)fmaxf(fmaf((float)sv.y, dd, bv.y) + a[i].y, 0.f);
            r.z = (_Float16)fmaxf(fmaf((float)sv.z, dd, bv.z) + a[i].z, 0.f);
            r.w = (_Float16)fmaxf(fmaf((float)sv.w, dd, bv.w) + a[i].w, 0.f);
            *(half4f*)&sa[(wid * 4 + i) * 72 + (q << 2)] = r;
        }
    }
    __syncthreads();

    int r16 = lane & 15, kg = lane >> 4;
    f32x4 acc = {0.f, 0.f, 0.f, 0.f};
    const _Float16* wp = (const _Float16*)W2T + (size_t)(wid * 16 + r16) * HIDDEN + kg * 8;
    #pragma unroll
    for (int kt = 0; kt < 2; ++kt) {
        half8 av = *(const half8*)&sa[r16 * 72 + kt * 32 + kg * 8];
        half8 b = *(const half8*)(wp + kt * 32);
        acc = __builtin_amdgcn_mfma_f32_16x16x32_f16(av, b, acc, 0, 0, 0);
    }
    int col = wid * 16 + r16;
    int nodebase = blockIdx.x * 16;
    #pragma unroll
    for (int r = 0; r < 4; ++r) {
        int row = nodebase + kg * 4 + r;
        h2[(size_t)row * HIDDEN + col] = __float2half(acc[r]);
    }
}

// ---------------- kC: quad conv2-gather + att (0..3124) || gbounds (3125..) ----------------
__global__ __launch_bounds__(256) void kC(const __half* __restrict__ h2,
                                          const unsigned* __restrict__ pk,
                                          const int* __restrict__ row_start,
                                          const float* __restrict__ dis,
                                          const float* __restrict__ b2,
                                          const float* __restrict__ att_w,
                                          const float* __restrict__ att_b,
                                          __half* __restrict__ agg2,
                                          float* __restrict__ att_s,
                                          const int* __restrict__ batch,
                                          int* gs, int* ge) {
    if (blockIdx.x >= NB_G2Q) {
        int n = (blockIdx.x - NB_G2Q) * 256 + threadIdx.x;
        if (n < N_NODES) {
            int b = batch[n];
            if (n == 0 || batch[n - 1] != b) gs[b] = n;
            if (n == N_NODES - 1 || batch[n + 1] != b) ge[b] = n + 1;
        }
        return;
    }
    int tid = threadIdx.x, wid = tid >> 6, lane = tid & 63;
    int g4 = lane >> 4, q = lane & 15;
    int base = blockIdx.x * 16 + wid * 4;   // 3125*16 = 50000
    int rs[5];
    #pragma unroll
    for (int i = 0; i < 5; ++i) rs[i] = row_start[base + i];

    float4 a[4];
    #pragma unroll
    for (int i = 0; i < 4; ++i) a[i] = make_float4(0.f, 0.f, 0.f, 0.f);
    gather4x(h2, pk, rs, lane, g4, q, a);
    #pragma unroll
    for (int i = 0; i < 4; ++i) xreduce(a[i]);

    float4 bv = *(const float4*)(b2 + (q << 2));
    float4 aw = *(const float4*)(att_w + (q << 2));
    float ab = att_b[0];
    #pragma unroll
    for (int i = 0; i < 4; ++i) {
        int node = base + i;
        float dd = dis[node]; dd *= dd;
        half4f sv = *(const half4f*)(h2 + (size_t)node * HIDDEN + (q << 2));
        float4 r;
        r.x = fmaxf(fmaf((float)sv.x, dd, bv.x) + a[i].x, 0.f);
        r.y = fmaxf(fmaf((float)sv.y, dd, bv.y) + a[i].y, 0.f);
        r.z = fmaxf(fmaf((float)sv.z, dd, bv.z) + a[i].z, 0.f);
        r.w = fmaxf(fmaf((float)sv.w, dd, bv.w) + a[i].w, 0.f);
        if (g4 == 0) {
            half4f rh;
            rh.x = (_Float16)r.x; rh.y = (_Float16)r.y;
            rh.z = (_Float16)r.z; rh.w = (_Float16)r.w;
            *(half4f*)(agg2 + (size_t)node * HIDDEN + (q << 2)) = rh;
        }
        float v = fmaf(r.x, aw.x, fmaf(r.y, aw.y, fmaf(r.z, aw.z, r.w * aw.w)));
        v += __shfl_xor(v, 1, 64); v += __shfl_xor(v, 2, 64);
        v += __shfl_xor(v, 4, 64); v += __shfl_xor(v, 8, 64);
        if (lane == 0) {
            float sc = v + ab;
            att_s[node] = (sc > 0.0f) ? sc : LEAKY * sc;
        }
    }
}

// ---------------- fused pool + head MLPs ----------------
__global__ __launch_bounds__(256) void k_pool_head(const __half* __restrict__ agg2,
                                                   const float* __restrict__ att_s,
                                                   const int* __restrict__ gs,
                                                   const int* __restrict__ ge,
                                                   const float* __restrict__ proj_w,
                                                   const float* __restrict__ proj_b,
                                                   const float* __restrict__ cls_w1,
                                                   const float* __restrict__ cls_b1,
                                                   const float* __restrict__ cls_w2,
                                                   const float* __restrict__ cls_b2,
                                                   float* __restrict__ out) {
    __shared__ float red[4];
    __shared__ float red2[4 * 64];
    __shared__ float sG[HIDDEN];
    __shared__ float sT1[EMBED];
    __shared__ float sT2[128];
    int gid = blockIdx.x;
    int tid = threadIdx.x, f = tid & 63, w = tid >> 6;
    int s = gs[gid], e = ge[gid];

    float m = -INFINITY;
    for (int n = s + tid; n < e; n += 256) m = fmaxf(m, att_s[n]);
    #pragma unroll
    for (int o = 32; o > 0; o >>= 1) m = fmaxf(m, __shfl_xor(m, o, 64));
    if (f == 0) red[w] = m;
    __syncthreads();
    m = fmaxf(fmaxf(red[0], red[1]), fmaxf(red[2], red[3]));
    __syncthreads();

    float z = 0.0f;
    for (int n = s + tid; n < e; n += 256) z += expf(att_s[n] - m);
    #pragma unroll
    for (int o = 32; o > 0; o >>= 1) z += __shfl_xor(z, o, 64);
    if (f == 0) red[w] = z;
    __syncthreads();
    z = red[0] + red[1] + red[2] + red[3];
    float inv = (e > s) ? 1.0f / z : 0.0f;

    float acc = 0.0f;
    for (int n = s + w; n < e; n += 4)
        acc = fmaf(expf(att_s[n] - m) * inv,
                   __half2float(agg2[(size_t)n * HIDDEN + f]), acc);
    red2[w * 64 + f] = acc;
    __syncthreads();
    if (w == 0) sG[f] = red2[f] + red2[64 + f] + red2[128 + f] + red2[192 + f];
    __syncthreads();

    for (int c = tid; c < EMBED; c += 256) {
        float a = proj_b[c];
        #pragma unroll 8
        for (int k = 0; k < HIDDEN; ++k) a = fmaf(sG[k], proj_w[k * EMBED + c], a);
        sT1[c] = a;
    }
    __syncthreads();

    if (tid < 128) {
        float a = cls_b1[tid];
        for (int k = 0; k < EMBED; ++k) a = fmaf(sT1[k], cls_w1[k * 128 + tid], a);
        sT2[tid] = fmaxf(a, 0.f);
    }
    __syncthreads();

    if (tid < N_CLASSES) {
        float a = cls_b2[tid];
        #pragma unroll 8
        for (int k = 0; k < 128; ++k) a = fmaf(sT2[k], cls_w2[k * N_CLASSES + tid], a);
        out[gid * N_CLASSES + tid] = a;
    }
}

extern "C" void kernel_launch(void* const* d_in, const int* in_sizes, int n_in,
                              void* d_out, int out_size, void* d_ws, size_t ws_size,
                              hipStream_t stream) {
    const float* x      = (const float*)d_in[0];
    const int*   ei     = (const int*)d_in[1];
    const int*   batch  = (const int*)d_in[2];
    const float* W1     = (const float*)d_in[3];
    const float* b1     = (const float*)d_in[4];
    const float* W2     = (const float*)d_in[5];
    const float* b2     = (const float*)d_in[6];
    const float* att_w  = (const float*)d_in[7];
    const float* att_b  = (const float*)d_in[8];
    const float* proj_w = (const float*)d_in[9];
    const float* proj_b = (const float*)d_in[10];
    const float* cls_w1 = (const float*)d_in[11];
    const float* cls_b1 = (const float*)d_in[12];
    const float* cls_w2 = (const float*)d_in[13];
    const float* cls_b2 = (const float*)d_in[14];
    float* out = (float*)d_out;

    const int* e_src = ei;
    const int* e_dst = ei + N_EDGES;

    // workspace (float words; all offsets multiples of 32 -> 128B-aligned)
    float* base = (float*)d_ws;
    size_t o = 0;
    float*    dis       = base + o;              o += 50048;
    int*      deg_i     = (int*)(base + o);      o += 50048;
    int*      row_start = (int*)(base + o);      o += 50080;
    unsigned long long* aggs = (unsigned long long*)(base + o); o += 512;
    unsigned* pk        = (unsigned*)(base + o); o += 800000;
    __half*   h1        = (__half*)(base + o);   o += 1600000;
    __half*   h2        = (__half*)(base + o);   o += 1600000;
    __half*   agg2      = (__half*)(base + o);   o += 1600000;
    int*      rank      = (int*)agg2;            // alias: rank dead before agg2 written
    float*    att_s     = base + o;              o += 50048;
    int*      gs        = (int*)(base + o);      o += 512;
    int*      ge        = (int*)(base + o);      o += 512;
    __half*   W1T       = (__half*)(base + o);   o += 4096;
    __half*   W2T       = (__half*)(base + o);   o += 2048;

    const int NB_E  = (N_EDGES + 255) / 256;   // 3125
    const int NB_GG = N_NODES / 16;            // 3125

    kA<<<244, 256, 0, stream>>>(deg_i, gs, ge, aggs, W1, W1T, W2, W2T);
    k_deg_rank<<<NB_E, 256, 0, stream>>>(e_dst, deg_i, rank);
    k_scan<<<SCAN_BLOCKS, 256, 0, stream>>>(deg_i, row_start, aggs, dis);

    // fill || gemm1
    kB<<<NB_FILL + 782, 256, 0, stream>>>(e_src, e_dst, rank, row_start, dis, pk, x, W1T, h1);

    // conv1-aggregate + conv2-transform
    k_gg<<<NB_GG, 256, 0, stream>>>(h1, pk, row_start, dis, b1, W2T, h2);

    // conv2-aggregate + att || gbounds
    kC<<<NB_G2Q + SCAN_BLOCKS, 256, 0, stream>>>(h2, pk, row_start, dis, b2, att_w, att_b,
                                                 agg2, att_s, batch, gs, ge);

    // pooling + head
    k_pool_head<<<N_GRAPHS, 256, 0, stream>>>(agg2, att_s, gs, ge,
                                              proj_w, proj_b, cls_w1, cls_b1,
                                              cls_w2, cls_b2, out);
}